// Round 1
// baseline (570.111 us; speedup 1.0000x reference)
//
#include <hip/hip_runtime.h>
#include <hip/hip_bf16.h>

typedef __bf16 bf16;
typedef __bf16 bf16x4 __attribute__((ext_vector_type(4)));
typedef __bf16 bf16x8 __attribute__((ext_vector_type(8)));
typedef float  f32x4  __attribute__((ext_vector_type(4)));

#define M_DIM 8192
#define N_DIM 4096
#define K_DIM 4096

#define GLOBAL_AS __attribute__((address_space(1)))
#define LDS_AS    __attribute__((address_space(3)))

// ---------------- conversion kernels ----------------

__global__ __launch_bounds__(256) void cvt_input_bf16(const float4* __restrict__ in,
                                                      bf16x4* __restrict__ out) {
    int idx = blockIdx.x * 256 + threadIdx.x;
    float4 v = in[idx];
    bf16x4 o;
    o.x = (bf16)v.x; o.y = (bf16)v.y; o.z = (bf16)v.z; o.w = (bf16)v.w;
    out[idx] = o;
}

__global__ __launch_bounds__(256) void cvt_weight_bf16(const int4* __restrict__ in,
                                                       bf16x4* __restrict__ out) {
    int idx = blockIdx.x * 256 + threadIdx.x;
    int4 v = in[idx];
    bf16x4 o;
    o.x = (bf16)(float)v.x; o.y = (bf16)(float)v.y;
    o.z = (bf16)(float)v.z; o.w = (bf16)(float)v.w;
    out[idx] = o;
}

// ---------------- main GEMM (m97 structure) ----------------
// C[m][n] = sum_k A[m][k]*B[n][k]  (B = weight, already [N,K] row-major = B^T form)
// 128x128 tile / block, BK=32, 256 threads = 4 waves in 2x2, each wave 64x64 via
// 4x4 grid of mfma_f32_16x16x32_bf16.

__global__ __launch_bounds__(256, 2) void gemm_bt_bf16(const bf16* __restrict__ A,
                                                       const bf16* __restrict__ B,
                                                       const float* __restrict__ scales,
                                                       float* __restrict__ C) {
    __shared__ bf16 lds_a[128 * 32];
    __shared__ bf16 lds_b[128 * 32];

    const int tid  = threadIdx.x;
    const int wave = tid >> 6;
    const int lane = tid & 63;
    const int m0 = blockIdx.y * 128;
    const int n0 = blockIdx.x * 128;
    const int wm = (wave >> 1) * 64;   // wave's M offset in tile
    const int wn = (wave & 1) * 64;    // wave's N offset in tile

    // staging: issue i covers lds byte range [i*4096 + wave*1024 + lane*16, +16)
    // -> bf16 idx = i*2048 + wave*512 + lane*8 -> row = i*64 + wave*16 + (lane>>2), col = (lane&3)*8
    const int srow0 = wave * 16 + (lane >> 2);
    const int scol  = (lane & 3) * 8;

    const int la = lane & 15;          // fragment row (m or n within 16)
    const int lk = (lane >> 4) * 8;    // fragment k offset

    f32x4 acc[4][4] = {};

    for (int k0 = 0; k0 < K_DIM; k0 += 32) {
        __syncthreads();   // previous iteration's LDS reads done
#pragma unroll
        for (int i = 0; i < 2; ++i) {
            const int row = srow0 + i * 64;
            const bf16* gp = A + (size_t)(m0 + row) * K_DIM + k0 + scol;
            __builtin_amdgcn_global_load_lds((GLOBAL_AS const void*)gp,
                                             (LDS_AS void*)(lds_a + row * 32 + scol),
                                             16, 0, 0);
        }
#pragma unroll
        for (int i = 0; i < 2; ++i) {
            const int row = srow0 + i * 64;
            const bf16* gp = B + (size_t)(n0 + row) * K_DIM + k0 + scol;
            __builtin_amdgcn_global_load_lds((GLOBAL_AS const void*)gp,
                                             (LDS_AS void*)(lds_b + row * 32 + scol),
                                             16, 0, 0);
        }
        __syncthreads();   // staging visible

        bf16x8 af[4], bfg[4];
#pragma unroll
        for (int i = 0; i < 4; ++i)
            af[i] = *(const bf16x8*)(lds_a + (wm + i * 16 + la) * 32 + lk);
#pragma unroll
        for (int j = 0; j < 4; ++j)
            bfg[j] = *(const bf16x8*)(lds_b + (wn + j * 16 + la) * 32 + lk);
#pragma unroll
        for (int i = 0; i < 4; ++i)
#pragma unroll
            for (int j = 0; j < 4; ++j)
                acc[i][j] = __builtin_amdgcn_mfma_f32_16x16x32_bf16(af[i], bfg[j], acc[i][j], 0, 0, 0);
    }

    // epilogue: C/D layout col = lane&15 (N), row = (lane>>4)*4 + reg (M)
    const int crow = (lane >> 4) * 4;
#pragma unroll
    for (int j = 0; j < 4; ++j) {
        const int col = n0 + wn + j * 16 + la;
        const float s = scales[col];
#pragma unroll
        for (int i = 0; i < 4; ++i) {
            const int rowb = m0 + wm + i * 16 + crow;
#pragma unroll
            for (int r = 0; r < 4; ++r)
                C[(size_t)(rowb + r) * N_DIM + col] = acc[i][j][r] * s;
        }
    }
}

// ---------------- fallback: fused conversion staging (no workspace needed) ----------------

__global__ __launch_bounds__(256, 2) void gemm_fused(const float* __restrict__ A,
                                                     const int* __restrict__ B,
                                                     const float* __restrict__ scales,
                                                     float* __restrict__ C) {
    __shared__ bf16 lds_a[128 * 32];
    __shared__ bf16 lds_b[128 * 32];

    const int tid  = threadIdx.x;
    const int wave = tid >> 6;
    const int lane = tid & 63;
    const int m0 = blockIdx.y * 128;
    const int n0 = blockIdx.x * 128;
    const int wm = (wave >> 1) * 64;
    const int wn = (wave & 1) * 64;

    // staging: thread handles row = tid>>1, cols [(tid&1)*16, +16)
    const int sr = tid >> 1;
    const int sc = (tid & 1) * 16;

    const int la = lane & 15;
    const int lk = (lane >> 4) * 8;

    f32x4 acc[4][4] = {};

    for (int k0 = 0; k0 < K_DIM; k0 += 32) {
        __syncthreads();
        {
            const float* ga = A + (size_t)(m0 + sr) * K_DIM + k0 + sc;
            float4 v0 = *(const float4*)(ga + 0);
            float4 v1 = *(const float4*)(ga + 4);
            float4 v2 = *(const float4*)(ga + 8);
            float4 v3 = *(const float4*)(ga + 12);
            bf16x8 p0, p1;
            p0[0]=(bf16)v0.x; p0[1]=(bf16)v0.y; p0[2]=(bf16)v0.z; p0[3]=(bf16)v0.w;
            p0[4]=(bf16)v1.x; p0[5]=(bf16)v1.y; p0[6]=(bf16)v1.z; p0[7]=(bf16)v1.w;
            p1[0]=(bf16)v2.x; p1[1]=(bf16)v2.y; p1[2]=(bf16)v2.z; p1[3]=(bf16)v2.w;
            p1[4]=(bf16)v3.x; p1[5]=(bf16)v3.y; p1[6]=(bf16)v3.z; p1[7]=(bf16)v3.w;
            *(bf16x8*)(lds_a + sr * 32 + sc)     = p0;
            *(bf16x8*)(lds_a + sr * 32 + sc + 8) = p1;
        }
        {
            const int* gb = B + (size_t)(n0 + sr) * K_DIM + k0 + sc;
            int4 v0 = *(const int4*)(gb + 0);
            int4 v1 = *(const int4*)(gb + 4);
            int4 v2 = *(const int4*)(gb + 8);
            int4 v3 = *(const int4*)(gb + 12);
            bf16x8 p0, p1;
            p0[0]=(bf16)(float)v0.x; p0[1]=(bf16)(float)v0.y; p0[2]=(bf16)(float)v0.z; p0[3]=(bf16)(float)v0.w;
            p0[4]=(bf16)(float)v1.x; p0[5]=(bf16)(float)v1.y; p0[6]=(bf16)(float)v1.z; p0[7]=(bf16)(float)v1.w;
            p1[0]=(bf16)(float)v2.x; p1[1]=(bf16)(float)v2.y; p1[2]=(bf16)(float)v2.z; p1[3]=(bf16)(float)v2.w;
            p1[4]=(bf16)(float)v3.x; p1[5]=(bf16)(float)v3.y; p1[6]=(bf16)(float)v3.z; p1[7]=(bf16)(float)v3.w;
            *(bf16x8*)(lds_b + sr * 32 + sc)     = p0;
            *(bf16x8*)(lds_b + sr * 32 + sc + 8) = p1;
        }
        __syncthreads();

        bf16x8 af[4], bfg[4];
#pragma unroll
        for (int i = 0; i < 4; ++i)
            af[i] = *(const bf16x8*)(lds_a + (wm + i * 16 + la) * 32 + lk);
#pragma unroll
        for (int j = 0; j < 4; ++j)
            bfg[j] = *(const bf16x8*)(lds_b + (wn + j * 16 + la) * 32 + lk);
#pragma unroll
        for (int i = 0; i < 4; ++i)
#pragma unroll
            for (int j = 0; j < 4; ++j)
                acc[i][j] = __builtin_amdgcn_mfma_f32_16x16x32_bf16(af[i], bfg[j], acc[i][j], 0, 0, 0);
    }

    const int crow = (lane >> 4) * 4;
#pragma unroll
    for (int j = 0; j < 4; ++j) {
        const int col = n0 + wn + j * 16 + la;
        const float s = scales[col];
#pragma unroll
        for (int i = 0; i < 4; ++i) {
            const int rowb = m0 + wm + i * 16 + crow;
#pragma unroll
            for (int r = 0; r < 4; ++r)
                C[(size_t)(rowb + r) * N_DIM + col] = acc[i][j][r] * s;
        }
    }
}

// ---------------- launch ----------------

extern "C" void kernel_launch(void* const* d_in, const int* in_sizes, int n_in,
                              void* d_out, int out_size, void* d_ws, size_t ws_size,
                              hipStream_t stream) {
    const float* input  = (const float*)d_in[0];   // [M, K] fp32
    const int*   weight = (const int*)d_in[1];     // [N, K] int32 (int8 values)
    const float* scales = (const float*)d_in[2];   // [N] fp32
    float* out = (float*)d_out;                    // [M, N] fp32

    const size_t needA = (size_t)M_DIM * K_DIM * sizeof(bf16);   // 64 MiB
    const size_t needB = (size_t)N_DIM * K_DIM * sizeof(bf16);   // 32 MiB

    dim3 grid(N_DIM / 128, M_DIM / 128);

    if (ws_size >= needA + needB) {
        bf16* Abf = (bf16*)d_ws;
        bf16* Bbf = (bf16*)((char*)d_ws + needA);
        cvt_input_bf16<<<(M_DIM * (size_t)K_DIM / 4) / 256, 256, 0, stream>>>(
            (const float4*)input, (bf16x4*)Abf);
        cvt_weight_bf16<<<(N_DIM * (size_t)K_DIM / 4) / 256, 256, 0, stream>>>(
            (const int4*)weight, (bf16x4*)Bbf);
        gemm_bt_bf16<<<grid, 256, 0, stream>>>(Abf, Bbf, scales, out);
    } else {
        gemm_fused<<<grid, 256, 0, stream>>>(input, weight, scales, out);
    }
}

// Round 2
// 569.055 us; speedup vs baseline: 1.0019x; 1.0019x over previous
//
#include <hip/hip_runtime.h>
#include <hip/hip_bf16.h>

typedef __bf16 bf16;
typedef __bf16 bf16x4 __attribute__((ext_vector_type(4)));
typedef __bf16 bf16x8 __attribute__((ext_vector_type(8)));
typedef float  f32x4  __attribute__((ext_vector_type(4)));

#define M_DIM 8192
#define N_DIM 4096
#define K_DIM 4096

#define GLOBAL_AS __attribute__((address_space(1)))
#define LDS_AS    __attribute__((address_space(3)))

// ---------------- conversion kernels (32 B in / 16 B out per thread) ----------------

__global__ __launch_bounds__(256) void cvt_input_bf16(const float4* __restrict__ in,
                                                      bf16x8* __restrict__ out) {
    int idx = blockIdx.x * 256 + threadIdx.x;
    float4 v0 = in[2 * idx];
    float4 v1 = in[2 * idx + 1];
    bf16x8 o;
    o[0] = (bf16)v0.x; o[1] = (bf16)v0.y; o[2] = (bf16)v0.z; o[3] = (bf16)v0.w;
    o[4] = (bf16)v1.x; o[5] = (bf16)v1.y; o[6] = (bf16)v1.z; o[7] = (bf16)v1.w;
    out[idx] = o;
}

__global__ __launch_bounds__(256) void cvt_weight_bf16(const int4* __restrict__ in,
                                                       bf16x8* __restrict__ out) {
    int idx = blockIdx.x * 256 + threadIdx.x;
    int4 v0 = in[2 * idx];
    int4 v1 = in[2 * idx + 1];
    bf16x8 o;
    o[0] = (bf16)(float)v0.x; o[1] = (bf16)(float)v0.y;
    o[2] = (bf16)(float)v0.z; o[3] = (bf16)(float)v0.w;
    o[4] = (bf16)(float)v1.x; o[5] = (bf16)(float)v1.y;
    o[6] = (bf16)(float)v1.z; o[7] = (bf16)(float)v1.w;
    out[idx] = o;
}

// ---------------- main GEMM (m97 structure + XOR-swizzled LDS) ----------------
// C[m][n] = sum_k A[m][k]*B[n][k]  (B = weight [N,K] row-major = B^T form)
// 128x128 tile, BK=32, 256 threads = 4 waves (2x2), wave does 64x64 via 4x4
// mfma_f32_16x16x32_bf16.
//
// LDS swizzle: tile row is 32 bf16 = 64 B = 4 chunks of 16 B. Physical chunk
// slot p (fixed by global_load_lds: base + lane*16) holds logical colblk
// c_log = (p&3) ^ ((row>>1)&3). This spreads the 16 fragment rows of a
// quarter-wave ds_read_b128 across all 8 (bank-phase, quad) positions ->
// 2-way aliasing (free) instead of 8-way. Staged by permuting the *global*
// source address per lane (LDS side of global_load_lds can't scatter - m104).

__global__ __launch_bounds__(256, 2) void gemm_bt_bf16(const bf16* __restrict__ A,
                                                       const bf16* __restrict__ B,
                                                       const float* __restrict__ scales,
                                                       float* __restrict__ C) {
    __shared__ bf16 lds_a[128 * 32];
    __shared__ bf16 lds_b[128 * 32];

    const int tid  = threadIdx.x;
    const int wave = tid >> 6;
    const int lane = tid & 63;
    const int m0 = blockIdx.y * 128;
    const int n0 = blockIdx.x * 128;
    const int wm = (wave >> 1) * 64;   // wave's M offset in tile
    const int wn = (wave & 1) * 64;    // wave's N offset in tile

    // staging: issue i -> physical slot p = i*256 + tid; row = p>>2 = i*64 + (tid>>2);
    // phys chunk = tid&3; logical colblk = (tid&3) ^ ((row>>1)&3) = (tid&3) ^ ((tid>>3)&3)
    // (i*64 contributes 0 to (row>>1)&3).
    const int srow0 = tid >> 2;                               // + i*64
    const int scol  = (((tid & 3) ^ ((tid >> 3) & 3))) * 8;   // logical col in elements

    const int la = lane & 15;                                 // fragment row within 16
    const int lk = (((lane >> 4) ^ ((la >> 1) & 3))) * 8;     // swizzled k-chunk offset

    f32x4 acc[4][4] = {};

    for (int k0 = 0; k0 < K_DIM; k0 += 32) {
        __syncthreads();   // previous iteration's LDS reads done
#pragma unroll
        for (int i = 0; i < 2; ++i) {
            const int row = srow0 + i * 64;
            const bf16* gp = A + (size_t)(m0 + row) * K_DIM + k0 + scol;
            __builtin_amdgcn_global_load_lds((GLOBAL_AS const void*)gp,
                                             (LDS_AS void*)(lds_a + row * 32 + (tid & 3) * 8),
                                             16, 0, 0);
        }
#pragma unroll
        for (int i = 0; i < 2; ++i) {
            const int row = srow0 + i * 64;
            const bf16* gp = B + (size_t)(n0 + row) * K_DIM + k0 + scol;
            __builtin_amdgcn_global_load_lds((GLOBAL_AS const void*)gp,
                                             (LDS_AS void*)(lds_b + row * 32 + (tid & 3) * 8),
                                             16, 0, 0);
        }
        __syncthreads();   // staging visible

        bf16x8 af[4], bfg[4];
#pragma unroll
        for (int i = 0; i < 4; ++i)
            af[i] = *(const bf16x8*)(lds_a + (wm + i * 16 + la) * 32 + lk);
#pragma unroll
        for (int j = 0; j < 4; ++j)
            bfg[j] = *(const bf16x8*)(lds_b + (wn + j * 16 + la) * 32 + lk);
#pragma unroll
        for (int i = 0; i < 4; ++i)
#pragma unroll
            for (int j = 0; j < 4; ++j)
                acc[i][j] = __builtin_amdgcn_mfma_f32_16x16x32_bf16(af[i], bfg[j], acc[i][j], 0, 0, 0);
    }

    // epilogue: C/D layout col = lane&15 (N), row = (lane>>4)*4 + reg (M)
    const int crow = (lane >> 4) * 4;
#pragma unroll
    for (int j = 0; j < 4; ++j) {
        const int col = n0 + wn + j * 16 + la;
        const float s = scales[col];
#pragma unroll
        for (int i = 0; i < 4; ++i) {
            const int rowb = m0 + wm + i * 16 + crow;
#pragma unroll
            for (int r = 0; r < 4; ++r)
                C[(size_t)(rowb + r) * N_DIM + col] = acc[i][j][r] * s;
        }
    }
}

// ---------------- fallback: fused conversion staging (no workspace needed) ----------------

__global__ __launch_bounds__(256, 2) void gemm_fused(const float* __restrict__ A,
                                                     const int* __restrict__ B,
                                                     const float* __restrict__ scales,
                                                     float* __restrict__ C) {
    __shared__ bf16 lds_a[128 * 32];
    __shared__ bf16 lds_b[128 * 32];

    const int tid  = threadIdx.x;
    const int wave = tid >> 6;
    const int lane = tid & 63;
    const int m0 = blockIdx.y * 128;
    const int n0 = blockIdx.x * 128;
    const int wm = (wave >> 1) * 64;
    const int wn = (wave & 1) * 64;

    const int sr = tid >> 1;
    const int sc = (tid & 1) * 16;

    const int la = lane & 15;
    const int lk = (lane >> 4) * 8;

    f32x4 acc[4][4] = {};

    for (int k0 = 0; k0 < K_DIM; k0 += 32) {
        __syncthreads();
        {
            const float* ga = A + (size_t)(m0 + sr) * K_DIM + k0 + sc;
            float4 v0 = *(const float4*)(ga + 0);
            float4 v1 = *(const float4*)(ga + 4);
            float4 v2 = *(const float4*)(ga + 8);
            float4 v3 = *(const float4*)(ga + 12);
            bf16x8 p0, p1;
            p0[0]=(bf16)v0.x; p0[1]=(bf16)v0.y; p0[2]=(bf16)v0.z; p0[3]=(bf16)v0.w;
            p0[4]=(bf16)v1.x; p0[5]=(bf16)v1.y; p0[6]=(bf16)v1.z; p0[7]=(bf16)v1.w;
            p1[0]=(bf16)v2.x; p1[1]=(bf16)v2.y; p1[2]=(bf16)v2.z; p1[3]=(bf16)v2.w;
            p1[4]=(bf16)v3.x; p1[5]=(bf16)v3.y; p1[6]=(bf16)v3.z; p1[7]=(bf16)v3.w;
            *(bf16x8*)(lds_a + sr * 32 + sc)     = p0;
            *(bf16x8*)(lds_a + sr * 32 + sc + 8) = p1;
        }
        {
            const int* gb = B + (size_t)(n0 + sr) * K_DIM + k0 + sc;
            int4 v0 = *(const int4*)(gb + 0);
            int4 v1 = *(const int4*)(gb + 4);
            int4 v2 = *(const int4*)(gb + 8);
            int4 v3 = *(const int4*)(gb + 12);
            bf16x8 p0, p1;
            p0[0]=(bf16)(float)v0.x; p0[1]=(bf16)(float)v0.y; p0[2]=(bf16)(float)v0.z; p0[3]=(bf16)(float)v0.w;
            p0[4]=(bf16)(float)v1.x; p0[5]=(bf16)(float)v1.y; p0[6]=(bf16)(float)v1.z; p0[7]=(bf16)(float)v1.w;
            p1[0]=(bf16)(float)v2.x; p1[1]=(bf16)(float)v2.y; p1[2]=(bf16)(float)v2.z; p1[3]=(bf16)(float)v2.w;
            p1[4]=(bf16)(float)v3.x; p1[5]=(bf16)(float)v3.y; p1[6]=(bf16)(float)v3.z; p1[7]=(bf16)(float)v3.w;
            *(bf16x8*)(lds_b + sr * 32 + sc)     = p0;
            *(bf16x8*)(lds_b + sr * 32 + sc + 8) = p1;
        }
        __syncthreads();

        bf16x8 af[4], bfg[4];
#pragma unroll
        for (int i = 0; i < 4; ++i)
            af[i] = *(const bf16x8*)(lds_a + (wm + i * 16 + la) * 32 + lk);
#pragma unroll
        for (int j = 0; j < 4; ++j)
            bfg[j] = *(const bf16x8*)(lds_b + (wn + j * 16 + la) * 32 + lk);
#pragma unroll
        for (int i = 0; i < 4; ++i)
#pragma unroll
            for (int j = 0; j < 4; ++j)
                acc[i][j] = __builtin_amdgcn_mfma_f32_16x16x32_bf16(af[i], bfg[j], acc[i][j], 0, 0, 0);
    }

    const int crow = (lane >> 4) * 4;
#pragma unroll
    for (int j = 0; j < 4; ++j) {
        const int col = n0 + wn + j * 16 + la;
        const float s = scales[col];
#pragma unroll
        for (int i = 0; i < 4; ++i) {
            const int rowb = m0 + wm + i * 16 + crow;
#pragma unroll
            for (int r = 0; r < 4; ++r)
                C[(size_t)(rowb + r) * N_DIM + col] = acc[i][j][r] * s;
        }
    }
}

// ---------------- launch ----------------

extern "C" void kernel_launch(void* const* d_in, const int* in_sizes, int n_in,
                              void* d_out, int out_size, void* d_ws, size_t ws_size,
                              hipStream_t stream) {
    const float* input  = (const float*)d_in[0];   // [M, K] fp32
    const int*   weight = (const int*)d_in[1];     // [N, K] int32 (int8 values)
    const float* scales = (const float*)d_in[2];   // [N] fp32
    float* out = (float*)d_out;                    // [M, N] fp32

    const size_t needA = (size_t)M_DIM * K_DIM * sizeof(bf16);   // 64 MiB
    const size_t needB = (size_t)N_DIM * K_DIM * sizeof(bf16);   // 32 MiB

    dim3 grid(N_DIM / 128, M_DIM / 128);

    if (ws_size >= needA + needB) {
        bf16* Abf = (bf16*)d_ws;
        bf16* Bbf = (bf16*)((char*)d_ws + needA);
        cvt_input_bf16<<<(M_DIM * (size_t)K_DIM / 8) / 256, 256, 0, stream>>>(
            (const float4*)input, (bf16x8*)Abf);
        cvt_weight_bf16<<<(N_DIM * (size_t)K_DIM / 8) / 256, 256, 0, stream>>>(
            (const int4*)weight, (bf16x8*)Bbf);
        gemm_bt_bf16<<<grid, 256, 0, stream>>>(Abf, Bbf, scales, out);
    } else {
        gemm_fused<<<grid, 256, 0, stream>>>(input, weight, scales, out);
    }
}